// Round 8
// baseline (139.839 us; speedup 1.0000x reference)
//
#include <hip/hip_runtime.h>

#define BN 256   // batches
#define NN 256   // matrix dim
#define WL 8     // walk length

typedef __attribute__((ext_vector_type(4))) float f32x4;
typedef unsigned long long ull;

// Segment fence: kills LICM/hoisting of LDS loads across it (all memory
// appears clobbered), keeping the ds_read in-flight window small. Without
// this, all per-step A-frag loads are g-loop-invariant (S is read-only
// after the barrier) and LICM hoists ~256 VGPRs of A-frags out of the
// g-loop -> spill (proven R6->R7: fence dropped VGPR 128->80, WRITE 68->3MB).
#define SEG_FENCE() __asm__ volatile("" ::: "memory")

// ---- f32 -> fp8 e4m3fn (OCP), RNE; manual fallback if builtin absent -------
__device__ inline unsigned f2e4m3(float x) {
  union { float f; unsigned u; } v; v.f = x;
  if (v.f <= 0.0f) return 0;                       // inputs are >= 0 here
  int e = (int)((v.u >> 23) & 0xff) - 127;
  if (e < -9) return 0;
  if (e < -6) {                                    // subnormal: q = RNE(x*512)
    int qi = (int)(x * 512.0f + 0.5f);
    return qi > 7 ? 7u : (unsigned)qi;
  }
  unsigned r = v.u + 0x7ffff + ((v.u >> 20) & 1);  // RNE to 3 mantissa bits
  e = (int)((r >> 23) & 0xff) - 127;
  unsigned m = (r >> 20) & 7;
  return (unsigned)(((e + 7) << 3) | m);
}

__device__ inline unsigned pk4(float a, float b, float c, float d) {
#if __has_builtin(__builtin_amdgcn_cvt_pk_fp8_f32)
  int r = 0;
  r = __builtin_amdgcn_cvt_pk_fp8_f32(a, b, r, false);   // bytes 0,1
  r = __builtin_amdgcn_cvt_pk_fp8_f32(c, d, r, true);    // bytes 2,3
  return (unsigned)r;
#else
  return f2e4m3(a) | (f2e4m3(b) << 8) | (f2e4m3(c) << 16) | (f2e4m3(d) << 24);
#endif
}

// ---- fused kernel: one block (8 waves) per batch ---------------------------
// LDS: S = 64*P, fp8 e4m3, 256 B per row. Dword d (cols 4d..4d+3) of row r,
// with d = 8kt + 2q + h (kt=k-granule, q=MFMA quad, h=granule half), lives at
// dword position p4 = (h<<5) | (q<<3) | ((kt ^ (r&7)) & 7).
// Bank of a chain read (h,kt fixed per instr; lanes vary q,l16):
//   q*8 + ((kt^l16)&7)  -> all 32 banks, exactly 2 lanes each (l16, l16+8)
//   = 2-way, which is conflict-free on gfx950 (m136). The previous b64
//   XOR-swizzle was structurally 4-way (16 bank-pairs x 4 quads, different
//   rows) -> 5.24M conflict cycles in R7 counters. Prep writes (row fixed,
//   lanes vary kt,q,h) land q*8+((kt^c)&7) with pairs (l, l^1): also 2-way.
//
// Chain: bcur holds 64*P^{g-1} as fp8 B-frags (g=1: identity, unscaled).
// Step g: acc = S*bcur = 4096*P^g (64*P for g=1); diag = acc/4096;
// bnext = fp8(acc/64). mt-pair loop: bnext[lnt][pt] depends only on acc
// tiles {2pt, 2pt+1}, so each pair's acc retires into its B-frag via 8
// shuffles right after its 32 MFMAs. No barriers after the first, no
// global traffic except in/out.
__global__ __launch_bounds__(512, 1) void k_chain(const float* __restrict__ A,
                                                  float* __restrict__ out) {
  __shared__ unsigned char S[65536];
  int b  = blockIdx.x;
  int t  = threadIdx.x;
  int wi = t >> 6;                 // wave 0..7
  int l  = t & 63;
  int q  = l >> 4, l16 = l & 15;
  const float* Ab = A + (size_t)b * NN * NN;
  float* outb = out + (size_t)b * NN * WL;

  // ---- phase 1: prep. wave wi handles rows [32wi, 32wi+32).
  // lane l produces dword d = l of the row: kt = l>>3, q = (l>>1)&3, h = l&1.
  int wq  = (l >> 1) & 3;          // this lane's q-role as a producer
  int wkt = l >> 3;                // this lane's kt-role
  int wh  = l & 1;
  for (int r0 = wi * 32; r0 < wi * 32 + 32; r0 += 8) {
    float4 rv[8];                                   // 8-deep load pipeline
    #pragma unroll
    for (int i = 0; i < 8; i++)
      rv[i] = *(const float4*)(Ab + (size_t)(r0 + i) * NN + l * 4);
    #pragma unroll
    for (int i = 0; i < 8; i++) {
      int row = r0 + i;                             // wave-uniform
      float t0 = rv[i].x > 0.3f ? rv[i].x : 0.0f;
      float t1 = rv[i].y > 0.3f ? rv[i].y : 0.0f;
      float t2 = rv[i].z > 0.3f ? rv[i].z : 0.0f;
      float t3 = rv[i].w > 0.3f ? rv[i].w : 0.0f;
      float s = (t0 + t1) + (t2 + t3);
      #pragma unroll
      for (int o = 32; o; o >>= 1) s += __shfl_xor(s, o);
      float dinv = s > 0.0f ? 1.0f / s : 0.0f;
      int rm = row & 3;                             // uniform
      float tv = rm == 0 ? t0 : rm == 1 ? t1 : rm == 2 ? t2 : t3;
      if (l == (row >> 2)) {
        outb[row * WL + 0] = 1.0f;
        outb[row * WL + 1] = tv * dinv;             // diag(P), exact f32
      }
      float sc = dinv * 64.0f;                      // store S = 64*P
      unsigned pkd = pk4(t0 * sc, t1 * sc, t2 * sc, t3 * sc);
      unsigned p4 = (unsigned)((wh << 5) | (wq << 3) | ((wkt ^ (row & 7)) & 7));
      *(unsigned*)&S[row * 256 + p4 * 4] = pkd;
    }
  }
  __syncthreads();   // S complete; read-only hereafter

  // ---- phase 2: identity B-frags (X0 = I). B[k][n]=1 iff k==n,
  // n = 32wi+16lnt+l16, k = 32kt+8q+j  ->  kt==wi, q==2lnt+(l16>>3), j=l16&7.
  long bcur[2][8], bnext[2][8];
  #pragma unroll
  for (int lnt = 0; lnt < 2; lnt++)
    #pragma unroll
    for (int kt = 0; kt < 8; kt++)
      bcur[lnt][kt] = (kt == wi && q == 2 * lnt + (l16 >> 3))
                        ? (long)(0x38ull << (8 * (l16 & 7)))   // e4m3 1.0
                        : 0L;

  // ---- phase 3: chain, mt-pair structured. g-loop MUST stay rolled and
  // fenced so per-step A-frag loads are re-issued per segment, not hoisted.
  const float invQ = 1.0f / 4096.0f;
  const float inv64 = 1.0f / 64.0f;
  #pragma unroll 1
  for (int g = 1; g <= 7; g++) {
    float osc = (g == 1) ? 1.0f : inv64;            // bnext scale
    #pragma unroll
    for (int pt = 0; pt < 8; pt++) {                // tiles mt = 2pt, 2pt+1
      SEG_FENCE();
      f32x4 acc[2][2];
      acc[0][0] = (f32x4){0.f, 0.f, 0.f, 0.f};
      acc[0][1] = (f32x4){0.f, 0.f, 0.f, 0.f};
      acc[1][0] = (f32x4){0.f, 0.f, 0.f, 0.f};
      acc[1][1] = (f32x4){0.f, 0.f, 0.f, 0.f};
      int base0 = (32 * pt + l16) * 256;            // row0 byte base
      int base1 = base0 + 16 * 256;                 // row1 = row0 + 16
      #pragma unroll
      for (int kt = 0; kt < 8; kt++) {
        int off = ((q << 3) | ((kt ^ (l16 & 7)) & 7)) << 2;   // h=0 dword
        unsigned d00 = *(const unsigned*)&S[base0 + off];
        unsigned d01 = *(const unsigned*)&S[base0 + off + 128]; // h=1
        unsigned d10 = *(const unsigned*)&S[base1 + off];
        unsigned d11 = *(const unsigned*)&S[base1 + off + 128];
        long a0 = (long)(((ull)d01 << 32) | d00);
        long a1 = (long)(((ull)d11 << 32) | d10);
        acc[0][0] = __builtin_amdgcn_mfma_f32_16x16x32_fp8_fp8(a0, bcur[0][kt], acc[0][0], 0, 0, 0);
        acc[0][1] = __builtin_amdgcn_mfma_f32_16x16x32_fp8_fp8(a0, bcur[1][kt], acc[0][1], 0, 0, 0);
        acc[1][0] = __builtin_amdgcn_mfma_f32_16x16x32_fp8_fp8(a1, bcur[0][kt], acc[1][0], 0, 0, 0);
        acc[1][1] = __builtin_amdgcn_mfma_f32_16x16x32_fp8_fp8(a1, bcur[1][kt], acc[1][1], 0, 0, 0);
      }
      // diag(P^g): C layout col=l16, row=4q+r. Diagonal tiles: pt==wi,
      // tile 2pt <-> lnt=0 (acc[0][0]), tile 2pt+1 <-> lnt=1 (acc[1][1]).
      if (g >= 2 && pt == wi && (l16 >> 2) == q) {
        int r = l16 & 3;
        outb[(32 * pt + l16) * WL + g]      = acc[0][0][r] * invQ;
        outb[(32 * pt + 16 + l16) * WL + g] = acc[1][1][r] * invQ;
      }
      if (g < 7) {
        // acc -> bnext[.][pt]: frag dword d, quad q needs tile 2pt+(q>>1),
        // source quad_c = 2(q&1)+d, same l16.
        unsigned pkv[2][2];
        #pragma unroll
        for (int mtl = 0; mtl < 2; mtl++)
          #pragma unroll
          for (int lnt = 0; lnt < 2; lnt++)
            pkv[mtl][lnt] = pk4(acc[mtl][lnt][0] * osc, acc[mtl][lnt][1] * osc,
                                acc[mtl][lnt][2] * osc, acc[mtl][lnt][3] * osc);
        int src0 = ((q & 1) << 5) | l16;   // quad_c = 2(q&1)
        int src1 = src0 + 16;              // quad_c = 2(q&1)+1
        int hiq = q >> 1;
        #pragma unroll
        for (int lnt = 0; lnt < 2; lnt++) {
          unsigned lo0 = (unsigned)__shfl((int)pkv[0][lnt], src0);
          unsigned hi0 = (unsigned)__shfl((int)pkv[1][lnt], src0);
          unsigned lo1 = (unsigned)__shfl((int)pkv[0][lnt], src1);
          unsigned hi1 = (unsigned)__shfl((int)pkv[1][lnt], src1);
          unsigned d0 = hiq ? hi0 : lo0;
          unsigned d1 = hiq ? hi1 : lo1;
          bnext[lnt][pt] = (long)(((ull)d1 << 32) | d0);
        }
      }
    }
    if (g < 7) {
      #pragma unroll
      for (int lnt = 0; lnt < 2; lnt++)
        #pragma unroll
        for (int kt = 0; kt < 8; kt++)
          bcur[lnt][kt] = bnext[lnt][kt];
    }
  }
}

extern "C" void kernel_launch(void* const* d_in, const int* in_sizes, int n_in,
                              void* d_out, int out_size, void* d_ws, size_t ws_size,
                              hipStream_t stream) {
  const float* A = (const float*)d_in[0];
  float* out = (float*)d_out;
  k_chain<<<BN, 512, 0, stream>>>(A, out);
}

// Round 9
// 131.280 us; speedup vs baseline: 1.0652x; 1.0652x over previous
//
#include <hip/hip_runtime.h>

#define BN 256   // batches
#define NN 256   // matrix dim
#define WL 8     // walk length

typedef __attribute__((ext_vector_type(4))) float f32x4;
typedef unsigned long long ull;

// Segment fence: kills LICM/hoisting of LDS loads across it (all memory
// appears clobbered), keeping the ds_read in-flight window small. Without
// this, all per-step A-frag loads are g-loop-invariant (S is read-only
// after the barrier) and LICM hoists ~256 VGPRs of A-frags out of the
// g-loop -> spill (proven R6->R7: fence dropped VGPR 128->80, WRITE 68->3MB).
#define SEG_FENCE() __asm__ volatile("" ::: "memory")

// ---- f32 -> fp8 e4m3fn (OCP), RNE; manual fallback if builtin absent -------
__device__ inline unsigned f2e4m3(float x) {
  union { float f; unsigned u; } v; v.f = x;
  if (v.f <= 0.0f) return 0;                       // inputs are >= 0 here
  int e = (int)((v.u >> 23) & 0xff) - 127;
  if (e < -9) return 0;
  if (e < -6) {                                    // subnormal: q = RNE(x*512)
    int qi = (int)(x * 512.0f + 0.5f);
    return qi > 7 ? 7u : (unsigned)qi;
  }
  unsigned r = v.u + 0x7ffff + ((v.u >> 20) & 1);  // RNE to 3 mantissa bits
  e = (int)((r >> 23) & 0xff) - 127;
  unsigned m = (r >> 20) & 7;
  return (unsigned)(((e + 7) << 3) | m);
}

__device__ inline unsigned pk4(float a, float b, float c, float d) {
#if __has_builtin(__builtin_amdgcn_cvt_pk_fp8_f32)
  int r = 0;
  r = __builtin_amdgcn_cvt_pk_fp8_f32(a, b, r, false);   // bytes 0,1
  r = __builtin_amdgcn_cvt_pk_fp8_f32(c, d, r, true);    // bytes 2,3
  return (unsigned)r;
#else
  return f2e4m3(a) | (f2e4m3(b) << 8) | (f2e4m3(c) << 16) | (f2e4m3(d) << 24);
#endif
}

// ---- fused kernel: one block (16 waves, 1024 thr) per batch ----------------
// LDS: S = 64*P, fp8 e4m3, row-major with 8B-granule XOR swizzle (R7 layout):
//   byte(row,col) at row*256 + ((col>>3) ^ (row&31))*8 + (col&7)
// A-frag b64 bank-pair = ((4kt+q)^l16)&15: all 16 residues once per q =
// 4 accesses/bank-pair = data-minimum -> conflict-free. (R8's b32 split
// chased the SQ_LDS_BANK_CONFLICT counter, which also counts free 2-way
// aliasing from bpermute/writes -- it regressed; reverted.)
//
// Chain: bcur holds 64*P^{g-1} as fp8 B-frags for the wave's 16-col strip
// (g=1: identity, unscaled). Step g: acc = S*bcur = 4096*P^g (64*P at g=1);
// diag = acc/4096; bnext = fp8(acc/64). Per mt-pair segment pt: 16 b64
// A-reads + 16 MFMA, then tiles {2pt,2pt+1} retire into bnext[pt] via 4
// bpermutes. 16 waves/block = 4 waves/SIMD: latency hiding is the point
// (R7/R8 at 2 waves/SIMD sat at MfmaUtil 31%, VALU 28%, both pipes idle
// ~40% on intra-wave dependency chains).
__global__ __launch_bounds__(1024, 1) void k_chain(const float* __restrict__ A,
                                                   float* __restrict__ out) {
  __shared__ unsigned char S[65536];
  int b  = blockIdx.x;
  int t  = threadIdx.x;
  int wi = t >> 6;                 // wave 0..15
  int l  = t & 63;
  int q  = l >> 4, l16 = l & 15;
  const float* Ab = A + (size_t)b * NN * NN;
  float* outb = out + (size_t)b * NN * WL;

  // ---- phase 1: prep. wave wi handles rows [16wi, 16wi+16).
  for (int r0 = wi * 16; r0 < wi * 16 + 16; r0 += 8) {
    float4 rv[8];                                   // 8-deep load pipeline
    #pragma unroll
    for (int i = 0; i < 8; i++)
      rv[i] = *(const float4*)(Ab + (size_t)(r0 + i) * NN + l * 4);
    #pragma unroll
    for (int i = 0; i < 8; i++) {
      int row = r0 + i;                             // wave-uniform
      float t0 = rv[i].x > 0.3f ? rv[i].x : 0.0f;
      float t1 = rv[i].y > 0.3f ? rv[i].y : 0.0f;
      float t2 = rv[i].z > 0.3f ? rv[i].z : 0.0f;
      float t3 = rv[i].w > 0.3f ? rv[i].w : 0.0f;
      float s = (t0 + t1) + (t2 + t3);
      #pragma unroll
      for (int o = 32; o; o >>= 1) s += __shfl_xor(s, o);
      float dinv = s > 0.0f ? 1.0f / s : 0.0f;
      int rm = row & 3;                             // uniform
      float tv = rm == 0 ? t0 : rm == 1 ? t1 : rm == 2 ? t2 : t3;
      if (l == (row >> 2)) {
        outb[row * WL + 0] = 1.0f;
        outb[row * WL + 1] = tv * dinv;             // diag(P), exact f32
      }
      float sc = dinv * 64.0f;                      // store S = 64*P
      unsigned pkd = pk4(t0 * sc, t1 * sc, t2 * sc, t3 * sc);
      unsigned addr = row * 256 + ((((unsigned)l >> 1) ^ (row & 31)) << 3) + ((l & 1) << 2);
      *(unsigned*)&S[addr] = pkd;
    }
  }
  __syncthreads();   // S complete; read-only hereafter

  // ---- phase 2: identity B-frags (X0 = I) for the wave's 16-col strip.
  // n = 16wi + l16; B[k][n]=1 at k=n: kt = n>>5 = wi>>1,
  // q = (n&31)>>3 = (2wi + (l16>>3)) & 3, j = n&7 = l16&7.
  long bcur[8], bnext[8];
  int n = 16 * wi + l16;           // this lane's owned column
  #pragma unroll
  for (int kt = 0; kt < 8; kt++)
    bcur[kt] = (kt == (wi >> 1) && q == ((2 * wi + (l16 >> 3)) & 3))
                 ? (long)(0x38ull << (8 * (l16 & 7)))   // e4m3 1.0
                 : 0L;

  // ---- phase 3: chain, mt-pair structured. g-loop MUST stay rolled and
  // fenced so per-step A-frag loads are re-issued per segment, not hoisted.
  const float invQ = 1.0f / 4096.0f;
  const float inv64 = 1.0f / 64.0f;
  int dpt = wi >> 1, dmtl = wi & 1;   // segment/half holding this wave's diag
  #pragma unroll 1
  for (int g = 1; g <= 7; g++) {
    float osc = (g == 1) ? 1.0f : inv64;            // bnext scale
    #pragma unroll
    for (int pt = 0; pt < 8; pt++) {                // tiles mt = 2pt, 2pt+1
      SEG_FENCE();
      f32x4 acc0 = (f32x4){0.f, 0.f, 0.f, 0.f};
      f32x4 acc1 = (f32x4){0.f, 0.f, 0.f, 0.f};
      int row0 = 32 * pt + l16;
      int row1 = row0 + 16;
      #pragma unroll
      for (int kt = 0; kt < 8; kt++) {
        long a0 = *(const long*)&S[row0 * 256 + (((4 * kt + q) ^ (row0 & 31)) << 3)];
        long a1 = *(const long*)&S[row1 * 256 + (((4 * kt + q) ^ (row1 & 31)) << 3)];
        acc0 = __builtin_amdgcn_mfma_f32_16x16x32_fp8_fp8(a0, bcur[kt], acc0, 0, 0, 0);
        acc1 = __builtin_amdgcn_mfma_f32_16x16x32_fp8_fp8(a1, bcur[kt], acc1, 0, 0, 0);
      }
      // diag(P^g): C layout col=l16, row=4q+r. This wave's diag lives in
      // tile wi = 2*dpt + dmtl, at lanes with l16>>2 == q.
      if (g >= 2 && pt == dpt && (l16 >> 2) == q) {
        float dv = dmtl ? acc1[l16 & 3] : acc0[l16 & 3];
        outb[n * WL + g] = dv * invQ;
      }
      if (g < 7) {
        // acc -> bnext[pt]: frag dword d needs tile 2pt+(q>>1) (= acc[q>>1]),
        // source quad_c = 2(q&1)+d, same l16.
        unsigned pkv0 = pk4(acc0[0] * osc, acc0[1] * osc, acc0[2] * osc, acc0[3] * osc);
        unsigned pkv1 = pk4(acc1[0] * osc, acc1[1] * osc, acc1[2] * osc, acc1[3] * osc);
        int src0 = ((q & 1) << 5) | l16;   // quad_c = 2(q&1)
        int src1 = src0 + 16;              // quad_c = 2(q&1)+1
        unsigned lo0 = (unsigned)__shfl((int)pkv0, src0);
        unsigned hi0 = (unsigned)__shfl((int)pkv1, src0);
        unsigned lo1 = (unsigned)__shfl((int)pkv0, src1);
        unsigned hi1 = (unsigned)__shfl((int)pkv1, src1);
        unsigned d0 = (q >> 1) ? hi0 : lo0;
        unsigned d1 = (q >> 1) ? hi1 : lo1;
        bnext[pt] = (long)(((ull)d1 << 32) | d0);
      }
    }
    if (g < 7) {
      #pragma unroll
      for (int kt = 0; kt < 8; kt++)
        bcur[kt] = bnext[kt];
    }
  }
}

extern "C" void kernel_launch(void* const* d_in, const int* in_sizes, int n_in,
                              void* d_out, int out_size, void* d_ws, size_t ws_size,
                              hipStream_t stream) {
  const float* A = (const float*)d_in[0];
  float* out = (float*)d_out;
  k_chain<<<BN, 1024, 0, stream>>>(A, out);
}

// Round 10
// 129.314 us; speedup vs baseline: 1.0814x; 1.0152x over previous
//
#include <hip/hip_runtime.h>

#define BN 256   // batches
#define NN 256   // matrix dim
#define WL 8     // walk length

typedef __attribute__((ext_vector_type(4))) float f32x4;
typedef unsigned long long ull;

// Segment fence: kills LICM/hoisting of LDS loads across it (all memory
// appears clobbered). Without it, all per-step A-frag loads are
// g-loop-invariant (S is read-only after the barrier) and LICM hoists
// ~256 VGPRs of A-frags out of the g-loop -> spill (proven R6->R7: fence
// dropped VGPR 128->80, WRITE 68->3MB). Registers in SSA form (abuf, bcur)
// are NOT spilled by the clobber -- proven R7.
#define SEG_FENCE() __asm__ volatile("" ::: "memory")

// ---- f32 -> fp8 e4m3fn (OCP), RNE; manual fallback if builtin absent -------
__device__ inline unsigned f2e4m3(float x) {
  union { float f; unsigned u; } v; v.f = x;
  if (v.f <= 0.0f) return 0;                       // inputs are >= 0 here
  int e = (int)((v.u >> 23) & 0xff) - 127;
  if (e < -9) return 0;
  if (e < -6) {                                    // subnormal: q = RNE(x*512)
    int qi = (int)(x * 512.0f + 0.5f);
    return qi > 7 ? 7u : (unsigned)qi;
  }
  unsigned r = v.u + 0x7ffff + ((v.u >> 20) & 1);  // RNE to 3 mantissa bits
  e = (int)((r >> 23) & 0xff) - 127;
  unsigned m = (r >> 20) & 7;
  return (unsigned)(((e + 7) << 3) | m);
}

__device__ inline unsigned pk4(float a, float b, float c, float d) {
#if __has_builtin(__builtin_amdgcn_cvt_pk_fp8_f32)
  int r = 0;
  r = __builtin_amdgcn_cvt_pk_fp8_f32(a, b, r, false);   // bytes 0,1
  r = __builtin_amdgcn_cvt_pk_fp8_f32(c, d, r, true);    // bytes 2,3
  return (unsigned)r;
#else
  return f2e4m3(a) | (f2e4m3(b) << 8) | (f2e4m3(c) << 16) | (f2e4m3(d) << 24);
#endif
}

// ---- fused kernel: one block (16 waves, 1024 thr) per batch ----------------
// LDS: S = 64*P, fp8 e4m3, row-major with 8B-granule XOR swizzle:
//   byte(row,col) at row*256 + ((col>>3) ^ (row&31))*8 + (col&7)
// A-frag b64 bank-pair = ((4kt+q)^l16)&15: all 16 residues once per q =
// data-minimum -> conflict-free. (SQ_LDS_BANK_CONFLICT ~9M is benign 2-way
// counting from bpermutes/writes -- R8 chased it and regressed.)
//
// Chain: bcur holds 64*P^{g-1} as fp8 B-frags for the wave's 16-col strip
// (g=1: identity, unscaled). Step g: acc = S*bcur = 4096*P^g (64*P at g=1);
// diag = acc/4096; bnext = fp8(acc/64). Per mt-pair segment pt: 16 b64
// A-reads + 16 MFMA; tiles {2pt,2pt+1} retire into bnext[pt] via 4 shuffles.
//
// R10: A-frags are software-pipelined one segment ahead into a parity
// double-buffer (addresses are g- and data-independent, repeating every 8
// segments, so parity wraps cleanly across g). MFMA(pt) consumes regs
// loaded in window pt-1 -> the ~120cyc LDS latency is off the critical
// path (R9 stalled each segment on its own loads: both pipes <40% busy).
__global__ __launch_bounds__(1024, 1) void k_chain(const float* __restrict__ A,
                                                   float* __restrict__ out) {
  __shared__ unsigned char S[65536];
  int b  = blockIdx.x;
  int t  = threadIdx.x;
  int wi = t >> 6;                 // wave 0..15
  int l  = t & 63;
  int q  = l >> 4, l16 = l & 15;
  const float* Ab = A + (size_t)b * NN * NN;
  float* outb = out + (size_t)b * NN * WL;

  // ---- phase 1: prep. wave wi handles rows [16wi, 16wi+16).
  for (int r0 = wi * 16; r0 < wi * 16 + 16; r0 += 8) {
    float4 rv[8];                                   // 8-deep load pipeline
    #pragma unroll
    for (int i = 0; i < 8; i++)
      rv[i] = *(const float4*)(Ab + (size_t)(r0 + i) * NN + l * 4);
    #pragma unroll
    for (int i = 0; i < 8; i++) {
      int row = r0 + i;                             // wave-uniform
      float t0 = rv[i].x > 0.3f ? rv[i].x : 0.0f;
      float t1 = rv[i].y > 0.3f ? rv[i].y : 0.0f;
      float t2 = rv[i].z > 0.3f ? rv[i].z : 0.0f;
      float t3 = rv[i].w > 0.3f ? rv[i].w : 0.0f;
      float s = (t0 + t1) + (t2 + t3);
      #pragma unroll
      for (int o = 32; o; o >>= 1) s += __shfl_xor(s, o);
      float dinv = s > 0.0f ? 1.0f / s : 0.0f;
      int rm = row & 3;                             // uniform
      float tv = rm == 0 ? t0 : rm == 1 ? t1 : rm == 2 ? t2 : t3;
      if (l == (row >> 2)) {
        outb[row * WL + 0] = 1.0f;
        outb[row * WL + 1] = tv * dinv;             // diag(P), exact f32
      }
      float sc = dinv * 64.0f;                      // store S = 64*P
      unsigned pkd = pk4(t0 * sc, t1 * sc, t2 * sc, t3 * sc);
      unsigned addr = row * 256 + ((((unsigned)l >> 1) ^ (row & 31)) << 3) + ((l & 1) << 2);
      *(unsigned*)&S[addr] = pkd;
    }
  }
  __syncthreads();   // S complete; read-only hereafter

  // ---- phase 2: identity B-frags (X0 = I) for the wave's 16-col strip.
  // n = 16wi + l16; B[k][n]=1 at k=n: kt = wi>>1, q = (2wi+(l16>>3))&3, j=l16&7.
  long bcur[8], bnext[8];
  int n = 16 * wi + l16;           // this lane's owned column
  #pragma unroll
  for (int kt = 0; kt < 8; kt++)
    bcur[kt] = (kt == (wi >> 1) && q == ((2 * wi + (l16 >> 3)) & 3))
                 ? (long)(0x38ull << (8 * (l16 & 7)))   // e4m3 1.0
                 : 0L;

  // ---- phase 3: chain with one-segment-ahead A prefetch.
  const float invQ = 1.0f / 4096.0f;
  const float inv64 = 1.0f / 64.0f;
  int dpt = wi >> 1, dmtl = wi & 1;   // segment/half holding this wave's diag

  long abuf[2][2][8];                 // [parity][row01][kt]
  // preload segment 0 into parity 0
  {
    int r0 = l16, r1 = l16 + 16;
    #pragma unroll
    for (int kt = 0; kt < 8; kt++) {
      abuf[0][0][kt] = *(const long*)&S[r0 * 256 + (((4 * kt + q) ^ (r0 & 31)) << 3)];
      abuf[0][1][kt] = *(const long*)&S[r1 * 256 + (((4 * kt + q) ^ (r1 & 31)) << 3)];
    }
  }

  #pragma unroll 1
  for (int g = 1; g <= 7; g++) {
    float osc = (g == 1) ? 1.0f : inv64;            // bnext scale
    #pragma unroll
    for (int pt = 0; pt < 8; pt++) {                // tiles mt = 2pt, 2pt+1
      SEG_FENCE();
      const int cur = pt & 1;
      const int nxt = (pt + 1) & 1;
      const int pn  = (pt + 1) & 7;   // wraps to seg 0 for next g (same addrs)
      // prefetch next segment's A-frags; MFMA below uses parity `cur`,
      // already resident -> no full lgkm drain on the critical path.
      {
        int r0 = 32 * pn + l16, r1 = r0 + 16;
        #pragma unroll
        for (int kt = 0; kt < 8; kt++) {
          abuf[nxt][0][kt] = *(const long*)&S[r0 * 256 + (((4 * kt + q) ^ (r0 & 31)) << 3)];
          abuf[nxt][1][kt] = *(const long*)&S[r1 * 256 + (((4 * kt + q) ^ (r1 & 31)) << 3)];
        }
      }
      f32x4 acc0 = (f32x4){0.f, 0.f, 0.f, 0.f};
      f32x4 acc1 = (f32x4){0.f, 0.f, 0.f, 0.f};
      #pragma unroll
      for (int kt = 0; kt < 8; kt++) {
        acc0 = __builtin_amdgcn_mfma_f32_16x16x32_fp8_fp8(abuf[cur][0][kt], bcur[kt], acc0, 0, 0, 0);
        acc1 = __builtin_amdgcn_mfma_f32_16x16x32_fp8_fp8(abuf[cur][1][kt], bcur[kt], acc1, 0, 0, 0);
      }
      // diag(P^g): C layout col=l16, row=4q+r. This wave's diag lives in
      // tile wi = 2*dpt + dmtl, at lanes with l16>>2 == q.
      if (g >= 2 && pt == dpt && (l16 >> 2) == q) {
        float dv = dmtl ? acc1[l16 & 3] : acc0[l16 & 3];
        outb[n * WL + g] = dv * invQ;
      }
      if (g < 7) {
        // acc -> bnext[pt]: frag dword d needs tile 2pt+(q>>1) (= acc[q>>1]),
        // source quad_c = 2(q&1)+d, same l16.
        unsigned pkv0 = pk4(acc0[0] * osc, acc0[1] * osc, acc0[2] * osc, acc0[3] * osc);
        unsigned pkv1 = pk4(acc1[0] * osc, acc1[1] * osc, acc1[2] * osc, acc1[3] * osc);
        int src0 = ((q & 1) << 5) | l16;   // quad_c = 2(q&1)
        int src1 = src0 + 16;              // quad_c = 2(q&1)+1
        unsigned lo0 = (unsigned)__shfl((int)pkv0, src0);
        unsigned hi0 = (unsigned)__shfl((int)pkv1, src0);
        unsigned lo1 = (unsigned)__shfl((int)pkv0, src1);
        unsigned hi1 = (unsigned)__shfl((int)pkv1, src1);
        unsigned d0 = (q >> 1) ? hi0 : lo0;
        unsigned d1 = (q >> 1) ? hi1 : lo1;
        bnext[pt] = (long)(((ull)d1 << 32) | d0);
      }
    }
    if (g < 7) {
      #pragma unroll
      for (int kt = 0; kt < 8; kt++)
        bcur[kt] = bnext[kt];
    }
  }
}

extern "C" void kernel_launch(void* const* d_in, const int* in_sizes, int n_in,
                              void* d_out, int out_size, void* d_ws, size_t ws_size,
                              hipStream_t stream) {
  const float* A = (const float*)d_in[0];
  float* out = (float*)d_out;
  k_chain<<<BN, 1024, 0, stream>>>(A, out);
}